// Round 10
// baseline (241.171 us; speedup 1.0000x reference)
//
#include <hip/hip_runtime.h>
#include <hip/hip_fp16.h>

#define BOHR_F 0.5291772105638411f
#define HA_D   27.211386024367243
#define A1_F   0.4289f
#define A2_F   4.4407f
#define S6_F   1.0f
#define S8_F   0.7875f
#define KCN_F  16.0f
#define WF_F   4.0f
#define EPS_F  1.1920929e-07f

#define Q15_SCALE 32767.0f
#define Q15_INV   (1.0f/32767.0f)
#define DR_SCALE  512.0f
#define DR_INV    (1.0f/512.0f)
// atomic-fallback fixed point
#define CN_SCALE 8388608.0f
#define CN_INV   (1.0f/8388608.0f)

#define NELEM  95
#define C6PADH 32            // 25 halfs -> 32 (64B row)
#define NBLK   512           // bin/scatter grid
#define BSW    512           // bin/scatter block

__device__ __forceinline__ float smooth_cutoff(float dr, float r_on, float r_cut) {
    float r_c = r_cut * r_cut;
    float r_o = r_on * r_on;
    float r   = dr * dr;
    float den = (r_c - r_o);
    float t   = r_c - r;
    float inner = (dr < r_cut)
        ? (t * t * (r_c + 2.0f * r - 3.0f * r_o)) / (den * den * den)
        : 0.0f;
    return (dr < r_on) ? 1.0f : inner;
}

__device__ __forceinline__ float edge_m(float dr, float rc) {
    if (!(dr > 0.0f)) return 0.0f;
    float count = 1.0f / (1.0f + expf(-KCN_F * (rc / dr - 1.0f)));
    return smooth_cutoff(dr, 20.0f, 25.0f) * count;
}

__device__ __forceinline__ void u2f2(unsigned u, float& a, float& b) {
    __half2 h = __builtin_bit_cast(__half2, u);
    float2 f = __half22float2(h);
    a = f.x; b = f.y;
}

// per-edge energy from fp16 atom records + fp16 c6 row
__device__ __forceinline__ float edge_e(float dr, uint4 Ri, uint4 Rj,
                                        uint4 c0, uint4 c1, uint4 c2, uint4 c3) {
    float wi[5], wj[5], qi, qj;
    u2f2(Ri.x, wi[0], wi[1]); u2f2(Ri.y, wi[2], wi[3]); u2f2(Ri.z, wi[4], qi);
    u2f2(Rj.x, wj[0], wj[1]); u2f2(Rj.y, wj[2], wj[3]); u2f2(Rj.z, wj[4], qj);
    float ct[26];
    u2f2(c0.x, ct[0],  ct[1]);  u2f2(c0.y, ct[2],  ct[3]);
    u2f2(c0.z, ct[4],  ct[5]);  u2f2(c0.w, ct[6],  ct[7]);
    u2f2(c1.x, ct[8],  ct[9]);  u2f2(c1.y, ct[10], ct[11]);
    u2f2(c1.z, ct[12], ct[13]); u2f2(c1.w, ct[14], ct[15]);
    u2f2(c2.x, ct[16], ct[17]); u2f2(c2.y, ct[18], ct[19]);
    u2f2(c2.z, ct[20], ct[21]); u2f2(c2.w, ct[22], ct[23]);
    u2f2(c3.x, ct[24], ct[25]);
    float c6 = 0.0f;
#pragma unroll
    for (int a = 0; a < 5; ++a)
#pragma unroll
        for (int b = 0; b < 5; ++b)
            c6 += wj[a] * wi[b] * ct[a * 5 + b];
    float qq = 3.0f * qi * qj;
    float rr = A1_F * sqrtf(qq) + A2_F;
    float dr2 = dr * dr;
    float dr6 = dr2 * dr2 * dr2;
    float dr8 = dr6 * dr2;
    float rr2 = rr * rr;
    float rr6 = rr2 * rr2 * rr2;
    float rr8 = rr6 * rr2;
    float damped = -c6 * (S6_F / (dr6 + rr6) + S8_F * qq / (dr8 + rr8));
    return smooth_cutoff(dr, 55.0f, 60.0f) * damped * 0.5f;
}

// ---------------- prep ----------------
__global__ __launch_bounds__(256)
void k_prep_c6(const float* __restrict__ src, __half* __restrict__ dst, int ntot) {
    int o = blockIdx.x * blockDim.x + threadIdx.x;
    if (o >= ntot) return;
    int p = o >> 5;
    int t = o & 31;
    dst[o] = __float2half((t < 25) ? src[p * 25 + t] : 0.0f);
}

// rcovZ[a] = {f32 rcov[numbers[a]], u32 numbers[a]}
__global__ __launch_bounds__(256)
void k_prep_atom(const int* __restrict__ numbers, const float* __restrict__ rcov,
                 uint2* __restrict__ rcovZ, int n_atoms) {
    int a = blockIdx.x * blockDim.x + threadIdx.x;
    if (a >= n_atoms) return;
    int Z = numbers[a];
    rcovZ[a] = make_uint2(__float_as_uint(rcov[Z]), (unsigned)Z);
}

// ---------------- sort path ----------------
// Pass A: per-edge {w0 = i<<15|q15, w1 = j<<15|dr15}; optional zpair; hist.
template<bool ZP>
__global__ __launch_bounds__(BSW, 4)
void k_bin(const float* __restrict__ dr_vec,
           const int* __restrict__ idx_i, const int* __restrict__ idx_j,
           const uint2* __restrict__ rcovZ,
           unsigned* __restrict__ packed2,        // [E,2]
           unsigned short* __restrict__ zpairA,   // [E] (ZP only)
           unsigned* __restrict__ ghist,
           int n_edges, int nb) {
    __shared__ unsigned hist[256];
    if (threadIdx.x < 256) hist[threadIdx.x] = 0;
    __syncthreads();
    int nquad = (n_edges + 3) >> 2;
    int stride = gridDim.x * blockDim.x;
    for (int qd = blockIdx.x * blockDim.x + threadIdx.x; qd < nquad; qd += stride) {
        int e0 = qd << 2;
        int ne = n_edges - e0; if (ne > 4) ne = 4;
        if (ne == 4) {
            float4 v0 = *reinterpret_cast<const float4*>(dr_vec + 3 * e0);
            float4 v1 = *reinterpret_cast<const float4*>(dr_vec + 3 * e0 + 4);
            float4 v2 = *reinterpret_cast<const float4*>(dr_vec + 3 * e0 + 8);
            float drq[4];
            drq[0] = sqrtf(v0.x*v0.x + v0.y*v0.y + v0.z*v0.z) / BOHR_F;
            drq[1] = sqrtf(v0.w*v0.w + v1.x*v1.x + v1.y*v1.y) / BOHR_F;
            drq[2] = sqrtf(v1.z*v1.z + v1.w*v1.w + v2.x*v2.x) / BOHR_F;
            drq[3] = sqrtf(v2.y*v2.y + v2.z*v2.z + v2.w*v2.w) / BOHR_F;
            int4 i4 = *reinterpret_cast<const int4*>(idx_i + e0);
            int4 j4 = *reinterpret_cast<const int4*>(idx_j + e0);
            int ia[4] = { i4.x, i4.y, i4.z, i4.w };
            int ja[4] = { j4.x, j4.y, j4.z, j4.w };
            uint2 RiZ[4], RjZ[4];
#pragma unroll
            for (int k = 0; k < 4; ++k) { RiZ[k] = rcovZ[ia[k]]; RjZ[k] = rcovZ[ja[k]]; }
            unsigned w0[4], w1[4];
            unsigned short zz[4];
#pragma unroll
            for (int k = 0; k < 4; ++k) {
                float rc = __uint_as_float(RiZ[k].x) + __uint_as_float(RjZ[k].x);
                float m = edge_m(drq[k], rc);
                unsigned q = (unsigned)(m * Q15_SCALE + 0.5f);
                if (q > 0x7FFFu) q = 0x7FFFu;
                unsigned dq = (unsigned)(drq[k] * DR_SCALE + 0.5f);
                if (dq > 0x7FFFu) dq = 0x7FFFu;
                w0[k] = ((unsigned)ia[k] << 15) | q;
                w1[k] = ((unsigned)ja[k] << 15) | dq;
                zz[k] = (unsigned short)(RjZ[k].y * NELEM + RiZ[k].y);
                atomicAdd(&hist[ia[k] >> 9], 1u);
            }
            *reinterpret_cast<uint4*>(packed2 + 2 * e0) =
                make_uint4(w0[0], w1[0], w0[1], w1[1]);
            *reinterpret_cast<uint4*>(packed2 + 2 * e0 + 4) =
                make_uint4(w0[2], w1[2], w0[3], w1[3]);
            if (ZP)
                *reinterpret_cast<uint2*>(zpairA + e0) =
                    make_uint2((unsigned)zz[0] | ((unsigned)zz[1] << 16),
                               (unsigned)zz[2] | ((unsigned)zz[3] << 16));
        } else {
            for (int k = 0; k < ne; ++k) {
                int e = e0 + k;
                float x = dr_vec[3*e], y = dr_vec[3*e+1], z = dr_vec[3*e+2];
                float dr = sqrtf(x*x + y*y + z*z) / BOHR_F;
                int i = idx_i[e], j = idx_j[e];
                uint2 RiZ = rcovZ[i], RjZ = rcovZ[j];
                float m = edge_m(dr, __uint_as_float(RiZ.x) + __uint_as_float(RjZ.x));
                unsigned q = (unsigned)(m * Q15_SCALE + 0.5f);
                if (q > 0x7FFFu) q = 0x7FFFu;
                unsigned dq = (unsigned)(dr * DR_SCALE + 0.5f);
                if (dq > 0x7FFFu) dq = 0x7FFFu;
                packed2[2*e]   = ((unsigned)i << 15) | q;
                packed2[2*e+1] = ((unsigned)j << 15) | dq;
                if (ZP) zpairA[e] = (unsigned short)(RjZ.y * NELEM + RiZ.y);
                atomicAdd(&hist[i >> 9], 1u);
            }
        }
    }
    __syncthreads();
    if ((int)threadIdx.x < nb)
        ghist[(size_t)threadIdx.x * gridDim.x + blockIdx.x] = hist[threadIdx.x];
}

// Pass B1: per-bucket exclusive scan across NBLK block-counts; bucket totals.
__global__ __launch_bounds__(NBLK)
void k_scan_bucket(unsigned* __restrict__ ghist, unsigned* __restrict__ totals) {
    __shared__ unsigned s[NBLK];
    int b = blockIdx.x;
    int t = threadIdx.x;
    unsigned v = ghist[(size_t)b * NBLK + t];
    s[t] = v;
    __syncthreads();
    for (int off = 1; off < NBLK; off <<= 1) {
        unsigned x = (t >= off) ? s[t - off] : 0u;
        __syncthreads();
        s[t] += x;
        __syncthreads();
    }
    ghist[(size_t)b * NBLK + t] = s[t] - v;   // exclusive
    if (t == NBLK - 1) totals[b] = s[t];
}

// Pass B2: exclusive scan over bucket totals -> base[nb+1].
__global__ __launch_bounds__(256)
void k_scan_base(const unsigned* __restrict__ totals,
                 unsigned* __restrict__ base, int nb) {
    __shared__ unsigned s[256];
    int t = threadIdx.x;
    unsigned v = (t < nb) ? totals[t] : 0u;
    s[t] = v;
    __syncthreads();
    for (int off = 1; off < 256; off <<= 1) {
        unsigned x = (t >= off) ? s[t - off] : 0u;
        __syncthreads();
        s[t] += x;
        __syncthreads();
    }
    if (t < nb) base[t] = s[t] - v;
    if (t == 255) base[nb] = s[t];
}

// Pass C: scatter {w0,w1} (+zpair) into bucket-sorted order (bucket = w0>>24).
template<bool ZP>
__global__ __launch_bounds__(BSW, 4)
void k_scatter(const unsigned* __restrict__ packed2,
               const unsigned short* __restrict__ zpairA,
               const unsigned* __restrict__ ghist,
               const unsigned* __restrict__ base,
               uint2* __restrict__ pairs,
               unsigned short* __restrict__ zs,
               int n_edges, int nb) {
    __shared__ unsigned ofs[256];
    if ((int)threadIdx.x < nb)
        ofs[threadIdx.x] = base[threadIdx.x]
                         + ghist[(size_t)threadIdx.x * gridDim.x + blockIdx.x];
    __syncthreads();
    int nquad = (n_edges + 3) >> 2;
    int stride = gridDim.x * blockDim.x;
    for (int qd = blockIdx.x * blockDim.x + threadIdx.x; qd < nquad; qd += stride) {
        int e0 = qd << 2;
        int ne = n_edges - e0; if (ne > 4) ne = 4;
        if (ne == 4) {
            uint4 pA = *reinterpret_cast<const uint4*>(packed2 + 2 * e0);
            uint4 pB = *reinterpret_cast<const uint4*>(packed2 + 2 * e0 + 4);
            unsigned w0[4] = { pA.x, pA.z, pB.x, pB.z };
            unsigned w1[4] = { pA.y, pA.w, pB.y, pB.w };
            unsigned short zz[4];
            if (ZP) {
                uint2 z2 = *reinterpret_cast<const uint2*>(zpairA + e0);
                zz[0] = (unsigned short)(z2.x & 0xFFFFu);
                zz[1] = (unsigned short)(z2.x >> 16);
                zz[2] = (unsigned short)(z2.y & 0xFFFFu);
                zz[3] = (unsigned short)(z2.y >> 16);
            }
#pragma unroll
            for (int k = 0; k < 4; ++k) {
                unsigned pos = atomicAdd(&ofs[w0[k] >> 24], 1u);
                pairs[pos] = make_uint2(w0[k], w1[k]);
                if (ZP) zs[pos] = zz[k];
            }
        } else {
            for (int k = 0; k < ne; ++k) {
                int e = e0 + k;
                unsigned w0 = packed2[2*e], w1 = packed2[2*e+1];
                unsigned pos = atomicAdd(&ofs[w0 >> 24], 1u);
                pairs[pos] = make_uint2(w0, w1);
                if (ZP) zs[pos] = zpairA[e];
            }
        }
    }
}

// Pass D: per-bucket LDS reduce -> cn; fused weights -> rec {w0..4, r4r2, Z, 0}
__global__ __launch_bounds__(512)
void k_reduce_weights(const uint2* __restrict__ pairs,
                      const unsigned* __restrict__ base,
                      const int* __restrict__ numbers,
                      const float* __restrict__ ref_cn_table,
                      const float* __restrict__ r4r2,
                      __half* __restrict__ rec,
                      int n_atoms) {
    __shared__ unsigned hist[512];
    hist[threadIdx.x] = 0;
    __syncthreads();
    int b = blockIdx.x;
    unsigned start = base[b];
    unsigned end   = base[b + 1];
    for (unsigned k = start + threadIdx.x; k < end; k += 512) {
        unsigned p = pairs[k].x;
        atomicAdd(&hist[(p >> 15) & 511], p & 0x7FFFu);
    }
    __syncthreads();
    int a = (b << 9) + threadIdx.x;
    if (a < n_atoms) {
        float c = (float)hist[threadIdx.x] * Q15_INV;
        int Z = numbers[a];
        float w[5];
        float s = 0.0f;
#pragma unroll
        for (int r = 0; r < 5; ++r) {
            float rcn = ref_cn_table[Z * 5 + r];
            float d = rcn - c;
            float wv = (rcn >= 0.0f) ? expf(-WF_F * d * d) : 0.0f;
            w[r] = wv;
            s += wv;
        }
        float den = s + EPS_F;
        __half* rr = rec + (size_t)a * 8;
#pragma unroll
        for (int r = 0; r < 5; ++r) rr[r] = __float2half(w[r] / den);
        rr[5] = __float2half(r4r2[Z]);
        rr[6] = __float2half((float)Z);
        rr[7] = __float2half(0.0f);
    }
}

// ---------------- energy (sorted order) ----------------
// Streams pairs (+zs); gathers rec[i] (bucket-local, L1-hot), rec[j], c6 row.
template<bool ZS>
__global__ __launch_bounds__(256)
void k_energy_sorted(const uint2* __restrict__ pairs,
                     const unsigned short* __restrict__ zs,
                     const __half* __restrict__ rec,   // [N,8] halfs = 1 uint4
                     const __half* __restrict__ c6h,   // [95*95][32] halfs
                     double* __restrict__ e_acc,
                     int n_edges) {
    double local = 0.0;
    const uint4* recv = reinterpret_cast<const uint4*>(rec);
    int tid = blockIdx.x * blockDim.x + threadIdx.x;
    int stride = gridDim.x * blockDim.x;
    for (int e = tid; e < n_edges; e += stride) {
        uint2 pr = pairs[e];
        unsigned i = pr.x >> 15;
        unsigned j = pr.y >> 15;
        float dr = (float)(pr.y & 0x7FFFu) * DR_INV;
        uint4 Ri = recv[i];
        uint4 Rj = recv[j];
        int zp;
        if (ZS) {
            zp = (int)zs[e];
        } else {
            float zif, zjf, dum;
            u2f2(Ri.w, zif, dum);
            u2f2(Rj.w, zjf, dum);
            zp = (int)zjf * NELEM + (int)zif;
        }
        const uint4* cp = reinterpret_cast<const uint4*>(c6h + (size_t)zp * C6PADH);
        local += (double)edge_e(dr, Ri, Rj, cp[0], cp[1], cp[2], cp[3]);
    }

    __shared__ double sdata[4];
    for (int off = 32; off > 0; off >>= 1)
        local += __shfl_down(local, off, 64);
    int lane = threadIdx.x & 63;
    int wid  = threadIdx.x >> 6;
    if (lane == 0) sdata[wid] = local;
    __syncthreads();
    if (threadIdx.x == 0) {
        double s = sdata[0] + sdata[1] + sdata[2] + sdata[3];
        atomicAdd(e_acc, s);
    }
}

// ---------------- atomic fallback path (small ws only) ----------------
__global__ __launch_bounds__(256)
void k_edges_cn_atomic(const float* __restrict__ dr_vec,
                       const int* __restrict__ idx_i,
                       const int* __restrict__ idx_j,
                       const uint2* __restrict__ rcovZ,
                       unsigned* __restrict__ cn_u32,
                       int n_edges) {
    int e = blockIdx.x * blockDim.x + threadIdx.x;
    if (e >= n_edges) return;
    float x = dr_vec[3 * e + 0];
    float y = dr_vec[3 * e + 1];
    float z = dr_vec[3 * e + 2];
    float dr = sqrtf(x * x + y * y + z * z) / BOHR_F;
    int i = idx_i[e];
    int j = idx_j[e];
    uint2 RiZ = rcovZ[i], RjZ = rcovZ[j];
    float m = edge_m(dr, __uint_as_float(RiZ.x) + __uint_as_float(RjZ.x));
    unsigned q = (unsigned)(m * CN_SCALE + 0.5f);
    if (q) atomicAdd(&cn_u32[i], q);
}

__global__ __launch_bounds__(256)
void k_atom_weights_rec(const unsigned* __restrict__ cn_u32,
                        const int* __restrict__ numbers,
                        const float* __restrict__ ref_cn_table,
                        const float* __restrict__ r4r2,
                        __half* __restrict__ rec,
                        int n_atoms) {
    int a = blockIdx.x * blockDim.x + threadIdx.x;
    if (a >= n_atoms) return;
    float c = (float)cn_u32[a] * CN_INV;
    int Z = numbers[a];
    float w[5];
    float s = 0.0f;
#pragma unroll
    for (int r = 0; r < 5; ++r) {
        float rcn = ref_cn_table[Z * 5 + r];
        float d = rcn - c;
        float wv = (rcn >= 0.0f) ? expf(-WF_F * d * d) : 0.0f;
        w[r] = wv;
        s += wv;
    }
    float den = s + EPS_F;
    __half* rr = rec + (size_t)a * 8;
#pragma unroll
    for (int r = 0; r < 5; ++r) rr[r] = __float2half(w[r] / den);
    rr[5] = __float2half(r4r2[Z]);
    rr[6] = __float2half((float)Z);
    rr[7] = __float2half(0.0f);
}

// unsorted energy (fallback): recompute dr, Z from rec.
__global__ __launch_bounds__(256)
void k_energy_unsorted(const float* __restrict__ dr_vec,
                       const int* __restrict__ idx_i,
                       const int* __restrict__ idx_j,
                       const __half* __restrict__ rec,
                       const __half* __restrict__ c6h,
                       double* __restrict__ e_acc,
                       int n_edges) {
    double local = 0.0;
    const uint4* recv = reinterpret_cast<const uint4*>(rec);
    int tid = blockIdx.x * blockDim.x + threadIdx.x;
    int stride = gridDim.x * blockDim.x;
    for (int e = tid; e < n_edges; e += stride) {
        float x = dr_vec[3*e], y = dr_vec[3*e+1], z = dr_vec[3*e+2];
        float dr = sqrtf(x*x + y*y + z*z) / BOHR_F;
        int i = idx_i[e], j = idx_j[e];
        uint4 Ri = recv[i];
        uint4 Rj = recv[j];
        float zif, zjf, dum;
        u2f2(Ri.w, zif, dum);
        u2f2(Rj.w, zjf, dum);
        int zp = (int)zjf * NELEM + (int)zif;
        const uint4* cp = reinterpret_cast<const uint4*>(c6h + (size_t)zp * C6PADH);
        local += (double)edge_e(dr, Ri, Rj, cp[0], cp[1], cp[2], cp[3]);
    }
    __shared__ double sdata[4];
    for (int off = 32; off > 0; off >>= 1)
        local += __shfl_down(local, off, 64);
    int lane = threadIdx.x & 63;
    int wid  = threadIdx.x >> 6;
    if (lane == 0) sdata[wid] = local;
    __syncthreads();
    if (threadIdx.x == 0) {
        double s = sdata[0] + sdata[1] + sdata[2] + sdata[3];
        atomicAdd(e_acc, s);
    }
}

__global__ void k_finalize(const double* __restrict__ e_acc,
                           float* __restrict__ out) {
    out[0] = (float)(e_acc[0] * HA_D);
}

static inline size_t a16(size_t x) { return (x + 15) & ~(size_t)15; }

extern "C" void kernel_launch(void* const* d_in, const int* in_sizes, int n_in,
                              void* d_out, int out_size, void* d_ws, size_t ws_size,
                              hipStream_t stream) {
    const float* dr_vec      = (const float*)d_in[0];
    const float* ref_cn_tab  = (const float*)d_in[1];
    const float* ref_c6_tab  = (const float*)d_in[2];
    const float* r4r2        = (const float*)d_in[3];
    const float* rcov        = (const float*)d_in[4];
    const int*   numbers     = (const int*)d_in[5];
    const int*   idx         = (const int*)d_in[6];

    int n_atoms = in_sizes[5];
    int n_edges = in_sizes[6] / 2;
    const int* idx_i = idx;
    const int* idx_j = idx + n_edges;

    const int BS = 256;
    int nb = (n_atoms + 511) >> 9;
    int c6tot = NELEM * NELEM * C6PADH;

    char* ws = (char*)d_ws;
    double* e_acc = (double*)ws;

    // common prefix: [e_acc 16][rec N*16B][c6h][rcovZ N*8]
    size_t off_rec = 16;
    size_t off_c6p = a16(off_rec + (size_t)n_atoms * 8 * 2);
    size_t off_rcZ = a16(off_c6p + (size_t)c6tot * 2);
    size_t off_var = a16(off_rcZ + (size_t)n_atoms * 8);

    // tier1: [packed2 8E][zpairA 2E][pairs 8E][zs 2E][ghist][tot][base]
    size_t t1_packed = off_var;
    size_t t1_zpA    = a16(t1_packed + (size_t)n_edges * 8);
    size_t t1_pairs  = a16(t1_zpA + (size_t)n_edges * 2);
    size_t t1_zs     = a16(t1_pairs + (size_t)n_edges * 8);
    size_t t1_ghist  = a16(t1_zs + (size_t)n_edges * 2);
    size_t t1_tot    = a16(t1_ghist + (size_t)nb * NBLK * 4);
    size_t t1_base   = a16(t1_tot + (size_t)nb * 4);
    size_t need_t1   = t1_base + (size_t)(nb + 1) * 4;

    // tier2: [packed2 8E][pairs 8E][ghist][tot][base]
    size_t t2_packed = off_var;
    size_t t2_pairs  = a16(t2_packed + (size_t)n_edges * 8);
    size_t t2_ghist  = a16(t2_pairs + (size_t)n_edges * 8);
    size_t t2_tot    = a16(t2_ghist + (size_t)nb * NBLK * 4);
    size_t t2_base   = a16(t2_tot + (size_t)nb * 4);
    size_t need_t2   = t2_base + (size_t)(nb + 1) * 4;

    // tier3 (atomic): [cn N*4]
    size_t t3_cn   = off_var;
    size_t need_t3 = t3_cn + (size_t)n_atoms * 4;

    int grid_c6 = (c6tot + BS - 1) / BS;
    int grid_a  = (n_atoms + BS - 1) / BS;
    int grid_e1 = (n_edges + BS - 1) / BS;
    if (grid_e1 > 8192) grid_e1 = 8192;

    __half* rec   = (__half*)(ws + off_rec);
    __half* c6h   = (__half*)(ws + off_c6p);
    uint2*  rcovZ = (uint2*)(ws + off_rcZ);

    k_prep_c6<<<grid_c6, BS, 0, stream>>>(ref_c6_tab, c6h, c6tot);
    k_prep_atom<<<grid_a, BS, 0, stream>>>(numbers, rcov, rcovZ, n_atoms);

    bool sortable = (n_atoms <= (1 << 17)) && (nb <= 256);

    if (sortable && ws_size >= need_t2) {
        bool zsOK = (ws_size >= need_t1);
        unsigned*       packed2 = (unsigned*)(ws + (zsOK ? t1_packed : t2_packed));
        unsigned short* zpairA  = zsOK ? (unsigned short*)(ws + t1_zpA) : nullptr;
        uint2*          pairs   = (uint2*)(ws + (zsOK ? t1_pairs : t2_pairs));
        unsigned short* zs      = zsOK ? (unsigned short*)(ws + t1_zs) : nullptr;
        unsigned*       ghist   = (unsigned*)(ws + (zsOK ? t1_ghist : t2_ghist));
        unsigned*       totals  = (unsigned*)(ws + (zsOK ? t1_tot : t2_tot));
        unsigned*       base    = (unsigned*)(ws + (zsOK ? t1_base : t2_base));

        hipMemsetAsync(d_ws, 0, 16, stream);   // e_acc only

        if (zsOK)
            k_bin<true><<<NBLK, BSW, 0, stream>>>(dr_vec, idx_i, idx_j, rcovZ,
                packed2, zpairA, ghist, n_edges, nb);
        else
            k_bin<false><<<NBLK, BSW, 0, stream>>>(dr_vec, idx_i, idx_j, rcovZ,
                packed2, nullptr, ghist, n_edges, nb);

        k_scan_bucket<<<nb, NBLK, 0, stream>>>(ghist, totals);
        k_scan_base<<<1, 256, 0, stream>>>(totals, base, nb);

        if (zsOK)
            k_scatter<true><<<NBLK, BSW, 0, stream>>>(packed2, zpairA, ghist,
                base, pairs, zs, n_edges, nb);
        else
            k_scatter<false><<<NBLK, BSW, 0, stream>>>(packed2, nullptr, ghist,
                base, pairs, nullptr, n_edges, nb);

        k_reduce_weights<<<nb, 512, 0, stream>>>(pairs, base, numbers,
            ref_cn_tab, r4r2, rec, n_atoms);

        if (zsOK)
            k_energy_sorted<true><<<grid_e1, BS, 0, stream>>>(pairs, zs, rec,
                c6h, e_acc, n_edges);
        else
            k_energy_sorted<false><<<grid_e1, BS, 0, stream>>>(pairs, nullptr,
                rec, c6h, e_acc, n_edges);
    } else {
        unsigned* cn_u32 = (unsigned*)(ws + t3_cn);
        hipMemsetAsync(d_ws, 0, 16, stream);
        hipMemsetAsync(cn_u32, 0, (size_t)n_atoms * 4, stream);

        int grid_e = (n_edges + BS - 1) / BS;
        k_edges_cn_atomic<<<grid_e, BS, 0, stream>>>(dr_vec, idx_i, idx_j,
            rcovZ, cn_u32, n_edges);
        k_atom_weights_rec<<<grid_a, BS, 0, stream>>>(cn_u32, numbers,
            ref_cn_tab, r4r2, rec, n_atoms);
        k_energy_unsorted<<<grid_e1, BS, 0, stream>>>(dr_vec, idx_i, idx_j,
            rec, c6h, e_acc, n_edges);
    }

    k_finalize<<<1, 1, 0, stream>>>(e_acc, (float*)d_out);
}

// Round 11
// 157.674 us; speedup vs baseline: 1.5296x; 1.5296x over previous
//
#include <hip/hip_runtime.h>
#include <hip/hip_fp16.h>

#define BOHR_F 0.5291772105638411f
#define HA_D   27.211386024367243
#define A1_F   0.4289f
#define A2_F   4.4407f
#define S6_F   1.0f
#define S8_F   0.7875f
#define KCN_F  16.0f
#define WF_F   4.0f
#define EPS_F  1.1920929e-07f

#define Q15_SCALE 32767.0f
#define Q15_INV   (1.0f/32767.0f)
#define DR_SCALE  512.0f
#define DR_INV    (1.0f/512.0f)
#define CN_SCALE 8388608.0f
#define CN_INV   (1.0f/8388608.0f)

#define NELEM  95
#define C6PADH 32            // 25 halfs -> 32 (64B row)
#define NBLK   512           // bin/scatter grid
#define BSW    512           // bin/scatter block

__device__ __forceinline__ float smooth_cutoff(float dr, float r_on, float r_cut) {
    float r_c = r_cut * r_cut;
    float r_o = r_on * r_on;
    float r   = dr * dr;
    float den = (r_c - r_o);
    float t   = r_c - r;
    float inner = (dr < r_cut)
        ? (t * t * (r_c + 2.0f * r - 3.0f * r_o)) / (den * den * den)
        : 0.0f;
    return (dr < r_on) ? 1.0f : inner;
}

__device__ __forceinline__ float edge_m(float dr, float rc) {
    if (!(dr > 0.0f)) return 0.0f;
    float count = 1.0f / (1.0f + expf(-KCN_F * (rc / dr - 1.0f)));
    return smooth_cutoff(dr, 20.0f, 25.0f) * count;
}

__device__ __forceinline__ void u2f2(unsigned u, float& a, float& b) {
    __half2 h = __builtin_bit_cast(__half2, u);
    float2 f = __half22float2(h);
    a = f.x; b = f.y;
}

__device__ __forceinline__ int zfromR(uint4 R) {
    float z, dum;
    u2f2(R.w, z, dum);
    return (int)z;
}

// per-edge energy from fp16 atom records + fp16 c6 row
__device__ __forceinline__ float edge_e(float dr, uint4 Ri, uint4 Rj,
                                        uint4 c0, uint4 c1, uint4 c2, uint4 c3) {
    float wi[5], wj[5], qi, qj;
    u2f2(Ri.x, wi[0], wi[1]); u2f2(Ri.y, wi[2], wi[3]); u2f2(Ri.z, wi[4], qi);
    u2f2(Rj.x, wj[0], wj[1]); u2f2(Rj.y, wj[2], wj[3]); u2f2(Rj.z, wj[4], qj);
    float ct[26];
    u2f2(c0.x, ct[0],  ct[1]);  u2f2(c0.y, ct[2],  ct[3]);
    u2f2(c0.z, ct[4],  ct[5]);  u2f2(c0.w, ct[6],  ct[7]);
    u2f2(c1.x, ct[8],  ct[9]);  u2f2(c1.y, ct[10], ct[11]);
    u2f2(c1.z, ct[12], ct[13]); u2f2(c1.w, ct[14], ct[15]);
    u2f2(c2.x, ct[16], ct[17]); u2f2(c2.y, ct[18], ct[19]);
    u2f2(c2.z, ct[20], ct[21]); u2f2(c2.w, ct[22], ct[23]);
    u2f2(c3.x, ct[24], ct[25]);
    float c6 = 0.0f;
#pragma unroll
    for (int a = 0; a < 5; ++a)
#pragma unroll
        for (int b = 0; b < 5; ++b)
            c6 += wj[a] * wi[b] * ct[a * 5 + b];
    float qq = 3.0f * qi * qj;
    float rr = A1_F * sqrtf(qq) + A2_F;
    float dr2 = dr * dr;
    float dr6 = dr2 * dr2 * dr2;
    float dr8 = dr6 * dr2;
    float rr2 = rr * rr;
    float rr6 = rr2 * rr2 * rr2;
    float rr8 = rr6 * rr2;
    float damped = -c6 * (S6_F / (dr6 + rr6) + S8_F * qq / (dr8 + rr8));
    return smooth_cutoff(dr, 55.0f, 60.0f) * damped * 0.5f;
}

// ---------------- prep ----------------
__global__ __launch_bounds__(256)
void k_prep_c6(const float* __restrict__ src, __half* __restrict__ dst, int ntot) {
    int o = blockIdx.x * blockDim.x + threadIdx.x;
    if (o >= ntot) return;
    int p = o >> 5;
    int t = o & 31;
    dst[o] = __float2half((t < 25) ? src[p * 25 + t] : 0.0f);
}

// rcovZ[a] = {f32 rcov[numbers[a]], u32 numbers[a]}
__global__ __launch_bounds__(256)
void k_prep_atom(const int* __restrict__ numbers, const float* __restrict__ rcov,
                 uint2* __restrict__ rcovZ, int n_atoms) {
    int a = blockIdx.x * blockDim.x + threadIdx.x;
    if (a >= n_atoms) return;
    int Z = numbers[a];
    rcovZ[a] = make_uint2(__float_as_uint(rcov[Z]), (unsigned)Z);
}

// ---------------- sort path ----------------
// Pass A: per-edge {w0 = i<<15|q15, w1 = j<<15|dr15}; per-block bucket hist.
__global__ __launch_bounds__(BSW, 4)
void k_bin(const float* __restrict__ dr_vec,
           const int* __restrict__ idx_i, const int* __restrict__ idx_j,
           const uint2* __restrict__ rcovZ,
           unsigned* __restrict__ packed2,        // [E,2]
           unsigned* __restrict__ ghist,
           int n_edges, int nb) {
    __shared__ unsigned hist[256];
    if (threadIdx.x < 256) hist[threadIdx.x] = 0;
    __syncthreads();
    int nquad = (n_edges + 3) >> 2;
    int stride = gridDim.x * blockDim.x;
    for (int qd = blockIdx.x * blockDim.x + threadIdx.x; qd < nquad; qd += stride) {
        int e0 = qd << 2;
        int ne = n_edges - e0; if (ne > 4) ne = 4;
        if (ne == 4) {
            float4 v0 = *reinterpret_cast<const float4*>(dr_vec + 3 * e0);
            float4 v1 = *reinterpret_cast<const float4*>(dr_vec + 3 * e0 + 4);
            float4 v2 = *reinterpret_cast<const float4*>(dr_vec + 3 * e0 + 8);
            float drq[4];
            drq[0] = sqrtf(v0.x*v0.x + v0.y*v0.y + v0.z*v0.z) / BOHR_F;
            drq[1] = sqrtf(v0.w*v0.w + v1.x*v1.x + v1.y*v1.y) / BOHR_F;
            drq[2] = sqrtf(v1.z*v1.z + v1.w*v1.w + v2.x*v2.x) / BOHR_F;
            drq[3] = sqrtf(v2.y*v2.y + v2.z*v2.z + v2.w*v2.w) / BOHR_F;
            int4 i4 = *reinterpret_cast<const int4*>(idx_i + e0);
            int4 j4 = *reinterpret_cast<const int4*>(idx_j + e0);
            int ia[4] = { i4.x, i4.y, i4.z, i4.w };
            int ja[4] = { j4.x, j4.y, j4.z, j4.w };
            uint2 RiZ[4], RjZ[4];
#pragma unroll
            for (int k = 0; k < 4; ++k) { RiZ[k] = rcovZ[ia[k]]; RjZ[k] = rcovZ[ja[k]]; }
            unsigned w0[4], w1[4];
#pragma unroll
            for (int k = 0; k < 4; ++k) {
                float rc = __uint_as_float(RiZ[k].x) + __uint_as_float(RjZ[k].x);
                float m = edge_m(drq[k], rc);
                unsigned q = (unsigned)(m * Q15_SCALE + 0.5f);
                if (q > 0x7FFFu) q = 0x7FFFu;
                unsigned dq = (unsigned)(drq[k] * DR_SCALE + 0.5f);
                if (dq > 0x7FFFu) dq = 0x7FFFu;
                w0[k] = ((unsigned)ia[k] << 15) | q;
                w1[k] = ((unsigned)ja[k] << 15) | dq;
                atomicAdd(&hist[ia[k] >> 9], 1u);
            }
            *reinterpret_cast<uint4*>(packed2 + 2 * e0) =
                make_uint4(w0[0], w1[0], w0[1], w1[1]);
            *reinterpret_cast<uint4*>(packed2 + 2 * e0 + 4) =
                make_uint4(w0[2], w1[2], w0[3], w1[3]);
        } else {
            for (int k = 0; k < ne; ++k) {
                int e = e0 + k;
                float x = dr_vec[3*e], y = dr_vec[3*e+1], z = dr_vec[3*e+2];
                float dr = sqrtf(x*x + y*y + z*z) / BOHR_F;
                int i = idx_i[e], j = idx_j[e];
                uint2 RiZ = rcovZ[i], RjZ = rcovZ[j];
                float m = edge_m(dr, __uint_as_float(RiZ.x) + __uint_as_float(RjZ.x));
                unsigned q = (unsigned)(m * Q15_SCALE + 0.5f);
                if (q > 0x7FFFu) q = 0x7FFFu;
                unsigned dq = (unsigned)(dr * DR_SCALE + 0.5f);
                if (dq > 0x7FFFu) dq = 0x7FFFu;
                packed2[2*e]   = ((unsigned)i << 15) | q;
                packed2[2*e+1] = ((unsigned)j << 15) | dq;
                atomicAdd(&hist[i >> 9], 1u);
            }
        }
    }
    __syncthreads();
    if ((int)threadIdx.x < nb)
        ghist[(size_t)threadIdx.x * gridDim.x + blockIdx.x] = hist[threadIdx.x];
}

// Pass B1: per-bucket exclusive scan across NBLK block-counts; bucket totals.
__global__ __launch_bounds__(NBLK)
void k_scan_bucket(unsigned* __restrict__ ghist, unsigned* __restrict__ totals) {
    __shared__ unsigned s[NBLK];
    int b = blockIdx.x;
    int t = threadIdx.x;
    unsigned v = ghist[(size_t)b * NBLK + t];
    s[t] = v;
    __syncthreads();
    for (int off = 1; off < NBLK; off <<= 1) {
        unsigned x = (t >= off) ? s[t - off] : 0u;
        __syncthreads();
        s[t] += x;
        __syncthreads();
    }
    ghist[(size_t)b * NBLK + t] = s[t] - v;   // exclusive
    if (t == NBLK - 1) totals[b] = s[t];
}

// Pass B2: exclusive scan over bucket totals -> base[nb+1].
__global__ __launch_bounds__(256)
void k_scan_base(const unsigned* __restrict__ totals,
                 unsigned* __restrict__ base, int nb) {
    __shared__ unsigned s[256];
    int t = threadIdx.x;
    unsigned v = (t < nb) ? totals[t] : 0u;
    s[t] = v;
    __syncthreads();
    for (int off = 1; off < 256; off <<= 1) {
        unsigned x = (t >= off) ? s[t - off] : 0u;
        __syncthreads();
        s[t] += x;
        __syncthreads();
    }
    if (t < nb) base[t] = s[t] - v;
    if (t == 255) base[nb] = s[t];
}

// Pass C: scatter {w0,w1} into bucket-sorted order (bucket = w0>>24).
__global__ __launch_bounds__(BSW, 4)
void k_scatter(const unsigned* __restrict__ packed2,
               const unsigned* __restrict__ ghist,
               const unsigned* __restrict__ base,
               uint2* __restrict__ pairs,
               int n_edges, int nb) {
    __shared__ unsigned ofs[256];
    if ((int)threadIdx.x < nb)
        ofs[threadIdx.x] = base[threadIdx.x]
                         + ghist[(size_t)threadIdx.x * gridDim.x + blockIdx.x];
    __syncthreads();
    int nquad = (n_edges + 3) >> 2;
    int stride = gridDim.x * blockDim.x;
    for (int qd = blockIdx.x * blockDim.x + threadIdx.x; qd < nquad; qd += stride) {
        int e0 = qd << 2;
        int ne = n_edges - e0; if (ne > 4) ne = 4;
        if (ne == 4) {
            uint4 pA = *reinterpret_cast<const uint4*>(packed2 + 2 * e0);
            uint4 pB = *reinterpret_cast<const uint4*>(packed2 + 2 * e0 + 4);
            unsigned w0[4] = { pA.x, pA.z, pB.x, pB.z };
            unsigned w1[4] = { pA.y, pA.w, pB.y, pB.w };
#pragma unroll
            for (int k = 0; k < 4; ++k) {
                unsigned pos = atomicAdd(&ofs[w0[k] >> 24], 1u);
                pairs[pos] = make_uint2(w0[k], w1[k]);
            }
        } else {
            for (int k = 0; k < ne; ++k) {
                int e = e0 + k;
                unsigned w0 = packed2[2*e], w1 = packed2[2*e+1];
                unsigned pos = atomicAdd(&ofs[w0 >> 24], 1u);
                pairs[pos] = make_uint2(w0, w1);
            }
        }
    }
}

// Pass D: per-bucket LDS reduce -> cn; fused weights -> rec {w0..4, r4r2, Z, 0}
__global__ __launch_bounds__(512)
void k_reduce_weights(const uint2* __restrict__ pairs,
                      const unsigned* __restrict__ base,
                      const int* __restrict__ numbers,
                      const float* __restrict__ ref_cn_table,
                      const float* __restrict__ r4r2,
                      __half* __restrict__ rec,
                      int n_atoms) {
    __shared__ unsigned hist[512];
    hist[threadIdx.x] = 0;
    __syncthreads();
    int b = blockIdx.x;
    unsigned start = base[b];
    unsigned end   = base[b + 1];
    for (unsigned k = start + threadIdx.x; k < end; k += 512) {
        unsigned p = pairs[k].x;
        atomicAdd(&hist[(p >> 15) & 511], p & 0x7FFFu);
    }
    __syncthreads();
    int a = (b << 9) + threadIdx.x;
    if (a < n_atoms) {
        float c = (float)hist[threadIdx.x] * Q15_INV;
        int Z = numbers[a];
        float w[5];
        float s = 0.0f;
#pragma unroll
        for (int r = 0; r < 5; ++r) {
            float rcn = ref_cn_table[Z * 5 + r];
            float d = rcn - c;
            float wv = (rcn >= 0.0f) ? expf(-WF_F * d * d) : 0.0f;
            w[r] = wv;
            s += wv;
        }
        float den = s + EPS_F;
        __half* rr = rec + (size_t)a * 8;
#pragma unroll
        for (int r = 0; r < 5; ++r) rr[r] = __float2half(w[r] / den);
        rr[5] = __float2half(r4r2[Z]);
        rr[6] = __float2half((float)Z);
        rr[7] = __float2half(0.0f);
    }
}

// ---------------- energy (sorted order, 4-edge batch) ----------------
#define LOADC(p, z) do { \
    const uint4* _cp = reinterpret_cast<const uint4*>(c6h + (size_t)(z) * C6PADH); \
    p##0 = _cp[0]; p##1 = _cp[1]; p##2 = _cp[2]; p##3 = _cp[3]; } while (0)

__global__ __launch_bounds__(256, 1)
void k_energy_sorted(const uint2* __restrict__ pairs,
                     const __half* __restrict__ rec,   // [N,8] halfs = 1 uint4
                     const __half* __restrict__ c6h,   // [95*95][32] halfs
                     double* __restrict__ e_acc,
                     int n_edges) {
    double local = 0.0;
    const uint4* recv = reinterpret_cast<const uint4*>(rec);
    int nquad = n_edges >> 2;
    int tid = blockIdx.x * blockDim.x + threadIdx.x;
    int stride = gridDim.x * blockDim.x;
    for (int qd = tid; qd < nquad; qd += stride) {
        int e0 = qd << 2;
        // stream loads (coalesced): 4 edges = 2 x uint4
        uint4 pA = *reinterpret_cast<const uint4*>(pairs + e0);
        uint4 pB = *reinterpret_cast<const uint4*>(pairs + e0 + 2);
        unsigned i0 = pA.x >> 15, j0 = pA.y >> 15;
        unsigned i1 = pA.z >> 15, j1 = pA.w >> 15;
        unsigned i2 = pB.x >> 15, j2 = pB.y >> 15;
        unsigned i3 = pB.z >> 15, j3 = pB.w >> 15;
        float dr0 = (float)(pA.y & 0x7FFFu) * DR_INV;
        float dr1 = (float)(pA.w & 0x7FFFu) * DR_INV;
        float dr2 = (float)(pB.y & 0x7FFFu) * DR_INV;
        float dr3 = (float)(pB.w & 0x7FFFu) * DR_INV;
        // all 8 rec gathers issued together (independent addresses)
        uint4 Ri0 = recv[i0], Rj0 = recv[j0];
        uint4 Ri1 = recv[i1], Rj1 = recv[j1];
        uint4 Ri2 = recv[i2], Rj2 = recv[j2];
        uint4 Ri3 = recv[i3], Rj3 = recv[j3];
        // derive c6 row ids, issue all 16 row loads together
        int zp0 = zfromR(Rj0) * NELEM + zfromR(Ri0);
        int zp1 = zfromR(Rj1) * NELEM + zfromR(Ri1);
        int zp2 = zfromR(Rj2) * NELEM + zfromR(Ri2);
        int zp3 = zfromR(Rj3) * NELEM + zfromR(Ri3);
        uint4 a0, a1, a2, a3;   LOADC(a, zp0);
        uint4 b0, b1, b2, b3;   LOADC(b, zp1);
        uint4 c0, c1, c2, c3;   LOADC(c, zp2);
        uint4 d0, d1, d2, d3;   LOADC(d, zp3);
        local += (double)edge_e(dr0, Ri0, Rj0, a0, a1, a2, a3);
        local += (double)edge_e(dr1, Ri1, Rj1, b0, b1, b2, b3);
        local += (double)edge_e(dr2, Ri2, Rj2, c0, c1, c2, c3);
        local += (double)edge_e(dr3, Ri3, Rj3, d0, d1, d2, d3);
    }
    // tail edges
    for (int e = (nquad << 2) + tid; e < n_edges; e += stride) {
        uint2 pr = pairs[e];
        unsigned i = pr.x >> 15;
        unsigned j = pr.y >> 15;
        float dr = (float)(pr.y & 0x7FFFu) * DR_INV;
        uint4 Ri = recv[i];
        uint4 Rj = recv[j];
        int zp = zfromR(Rj) * NELEM + zfromR(Ri);
        const uint4* cp = reinterpret_cast<const uint4*>(c6h + (size_t)zp * C6PADH);
        local += (double)edge_e(dr, Ri, Rj, cp[0], cp[1], cp[2], cp[3]);
    }

    __shared__ double sdata[4];
    for (int off = 32; off > 0; off >>= 1)
        local += __shfl_down(local, off, 64);
    int lane = threadIdx.x & 63;
    int wid  = threadIdx.x >> 6;
    if (lane == 0) sdata[wid] = local;
    __syncthreads();
    if (threadIdx.x == 0) {
        double s = sdata[0] + sdata[1] + sdata[2] + sdata[3];
        atomicAdd(e_acc, s);
    }
}

// ---------------- atomic fallback path (small ws only) ----------------
__global__ __launch_bounds__(256)
void k_edges_cn_atomic(const float* __restrict__ dr_vec,
                       const int* __restrict__ idx_i,
                       const int* __restrict__ idx_j,
                       const uint2* __restrict__ rcovZ,
                       unsigned* __restrict__ cn_u32,
                       int n_edges) {
    int e = blockIdx.x * blockDim.x + threadIdx.x;
    if (e >= n_edges) return;
    float x = dr_vec[3 * e + 0];
    float y = dr_vec[3 * e + 1];
    float z = dr_vec[3 * e + 2];
    float dr = sqrtf(x * x + y * y + z * z) / BOHR_F;
    int i = idx_i[e];
    int j = idx_j[e];
    uint2 RiZ = rcovZ[i], RjZ = rcovZ[j];
    float m = edge_m(dr, __uint_as_float(RiZ.x) + __uint_as_float(RjZ.x));
    unsigned q = (unsigned)(m * CN_SCALE + 0.5f);
    if (q) atomicAdd(&cn_u32[i], q);
}

__global__ __launch_bounds__(256)
void k_atom_weights_rec(const unsigned* __restrict__ cn_u32,
                        const int* __restrict__ numbers,
                        const float* __restrict__ ref_cn_table,
                        const float* __restrict__ r4r2,
                        __half* __restrict__ rec,
                        int n_atoms) {
    int a = blockIdx.x * blockDim.x + threadIdx.x;
    if (a >= n_atoms) return;
    float c = (float)cn_u32[a] * CN_INV;
    int Z = numbers[a];
    float w[5];
    float s = 0.0f;
#pragma unroll
    for (int r = 0; r < 5; ++r) {
        float rcn = ref_cn_table[Z * 5 + r];
        float d = rcn - c;
        float wv = (rcn >= 0.0f) ? expf(-WF_F * d * d) : 0.0f;
        w[r] = wv;
        s += wv;
    }
    float den = s + EPS_F;
    __half* rr = rec + (size_t)a * 8;
#pragma unroll
    for (int r = 0; r < 5; ++r) rr[r] = __float2half(w[r] / den);
    rr[5] = __float2half(r4r2[Z]);
    rr[6] = __float2half((float)Z);
    rr[7] = __float2half(0.0f);
}

// unsorted energy (fallback): recompute dr, Z from rec.
__global__ __launch_bounds__(256)
void k_energy_unsorted(const float* __restrict__ dr_vec,
                       const int* __restrict__ idx_i,
                       const int* __restrict__ idx_j,
                       const __half* __restrict__ rec,
                       const __half* __restrict__ c6h,
                       double* __restrict__ e_acc,
                       int n_edges) {
    double local = 0.0;
    const uint4* recv = reinterpret_cast<const uint4*>(rec);
    int tid = blockIdx.x * blockDim.x + threadIdx.x;
    int stride = gridDim.x * blockDim.x;
    for (int e = tid; e < n_edges; e += stride) {
        float x = dr_vec[3*e], y = dr_vec[3*e+1], z = dr_vec[3*e+2];
        float dr = sqrtf(x*x + y*y + z*z) / BOHR_F;
        int i = idx_i[e], j = idx_j[e];
        uint4 Ri = recv[i];
        uint4 Rj = recv[j];
        int zp = zfromR(Rj) * NELEM + zfromR(Ri);
        const uint4* cp = reinterpret_cast<const uint4*>(c6h + (size_t)zp * C6PADH);
        local += (double)edge_e(dr, Ri, Rj, cp[0], cp[1], cp[2], cp[3]);
    }
    __shared__ double sdata[4];
    for (int off = 32; off > 0; off >>= 1)
        local += __shfl_down(local, off, 64);
    int lane = threadIdx.x & 63;
    int wid  = threadIdx.x >> 6;
    if (lane == 0) sdata[wid] = local;
    __syncthreads();
    if (threadIdx.x == 0) {
        double s = sdata[0] + sdata[1] + sdata[2] + sdata[3];
        atomicAdd(e_acc, s);
    }
}

__global__ void k_finalize(const double* __restrict__ e_acc,
                           float* __restrict__ out) {
    out[0] = (float)(e_acc[0] * HA_D);
}

static inline size_t a16(size_t x) { return (x + 15) & ~(size_t)15; }

extern "C" void kernel_launch(void* const* d_in, const int* in_sizes, int n_in,
                              void* d_out, int out_size, void* d_ws, size_t ws_size,
                              hipStream_t stream) {
    const float* dr_vec      = (const float*)d_in[0];
    const float* ref_cn_tab  = (const float*)d_in[1];
    const float* ref_c6_tab  = (const float*)d_in[2];
    const float* r4r2        = (const float*)d_in[3];
    const float* rcov        = (const float*)d_in[4];
    const int*   numbers     = (const int*)d_in[5];
    const int*   idx         = (const int*)d_in[6];

    int n_atoms = in_sizes[5];
    int n_edges = in_sizes[6] / 2;
    const int* idx_i = idx;
    const int* idx_j = idx + n_edges;

    const int BS = 256;
    int nb = (n_atoms + 511) >> 9;
    int c6tot = NELEM * NELEM * C6PADH;

    char* ws = (char*)d_ws;
    double* e_acc = (double*)ws;

    // common prefix: [e_acc 16][rec N*16B][c6h][rcovZ N*8]
    size_t off_rec = 16;
    size_t off_c6p = a16(off_rec + (size_t)n_atoms * 8 * 2);
    size_t off_rcZ = a16(off_c6p + (size_t)c6tot * 2);
    size_t off_var = a16(off_rcZ + (size_t)n_atoms * 8);

    // sort path: [packed2 8E][pairs 8E][ghist][tot][base]
    size_t s_packed = off_var;
    size_t s_pairs  = a16(s_packed + (size_t)n_edges * 8);
    size_t s_ghist  = a16(s_pairs + (size_t)n_edges * 8);
    size_t s_tot    = a16(s_ghist + (size_t)nb * NBLK * 4);
    size_t s_base   = a16(s_tot + (size_t)nb * 4);
    size_t need_s   = s_base + (size_t)(nb + 1) * 4;

    // atomic path: [cn N*4]
    size_t a_cn   = off_var;

    int grid_c6 = (c6tot + BS - 1) / BS;
    int grid_a  = (n_atoms + BS - 1) / BS;
    int nquad   = (n_edges + 3) >> 2;
    int grid_q  = (nquad + BS - 1) / BS;
    if (grid_q > 8192) grid_q = 8192;
    int grid_e1 = (n_edges + BS - 1) / BS;
    if (grid_e1 > 8192) grid_e1 = 8192;

    __half* rec   = (__half*)(ws + off_rec);
    __half* c6h   = (__half*)(ws + off_c6p);
    uint2*  rcovZ = (uint2*)(ws + off_rcZ);

    k_prep_c6<<<grid_c6, BS, 0, stream>>>(ref_c6_tab, c6h, c6tot);
    k_prep_atom<<<grid_a, BS, 0, stream>>>(numbers, rcov, rcovZ, n_atoms);

    bool sortable = (n_atoms <= (1 << 17)) && (nb <= 256);

    if (sortable && ws_size >= need_s) {
        unsigned* packed2 = (unsigned*)(ws + s_packed);
        uint2*    pairs   = (uint2*)(ws + s_pairs);
        unsigned* ghist   = (unsigned*)(ws + s_ghist);
        unsigned* totals  = (unsigned*)(ws + s_tot);
        unsigned* base    = (unsigned*)(ws + s_base);

        hipMemsetAsync(d_ws, 0, 16, stream);   // e_acc only

        k_bin<<<NBLK, BSW, 0, stream>>>(dr_vec, idx_i, idx_j, rcovZ,
            packed2, ghist, n_edges, nb);
        k_scan_bucket<<<nb, NBLK, 0, stream>>>(ghist, totals);
        k_scan_base<<<1, 256, 0, stream>>>(totals, base, nb);
        k_scatter<<<NBLK, BSW, 0, stream>>>(packed2, ghist, base, pairs,
                                            n_edges, nb);
        k_reduce_weights<<<nb, 512, 0, stream>>>(pairs, base, numbers,
            ref_cn_tab, r4r2, rec, n_atoms);
        k_energy_sorted<<<grid_q, BS, 0, stream>>>(pairs, rec, c6h, e_acc,
                                                   n_edges);
    } else {
        unsigned* cn_u32 = (unsigned*)(ws + a_cn);
        hipMemsetAsync(d_ws, 0, 16, stream);
        hipMemsetAsync(cn_u32, 0, (size_t)n_atoms * 4, stream);

        int grid_e = (n_edges + BS - 1) / BS;
        k_edges_cn_atomic<<<grid_e, BS, 0, stream>>>(dr_vec, idx_i, idx_j,
            rcovZ, cn_u32, n_edges);
        k_atom_weights_rec<<<grid_a, BS, 0, stream>>>(cn_u32, numbers,
            ref_cn_tab, r4r2, rec, n_atoms);
        k_energy_unsorted<<<grid_e1, BS, 0, stream>>>(dr_vec, idx_i, idx_j,
            rec, c6h, e_acc, n_edges);
    }

    k_finalize<<<1, 1, 0, stream>>>(e_acc, (float*)d_out);
}

// Round 12
// 150.348 us; speedup vs baseline: 1.6041x; 1.0487x over previous
//
#include <hip/hip_runtime.h>
#include <hip/hip_fp16.h>

#define BOHR_F 0.5291772105638411f
#define HA_D   27.211386024367243
#define A1_F   0.4289f
#define A2_F   4.4407f
#define S6_F   1.0f
#define S8_F   0.7875f
#define KCN_F  16.0f
#define WF_F   4.0f
#define EPS_F  1.1920929e-07f

#define Q15_SCALE 32767.0f
#define Q15_INV   (1.0f/32767.0f)
#define DR_SCALE  512.0f
#define DR_INV    (1.0f/512.0f)
#define CN_SCALE 8388608.0f
#define CN_INV   (1.0f/8388608.0f)

#define NELEM  95
#define NBLK   512           // hist/scatter grid (must match between the two)
#define BSW    512           // hist/scatter block

__device__ __forceinline__ float smooth_cutoff(float dr, float r_on, float r_cut) {
    float r_c = r_cut * r_cut;
    float r_o = r_on * r_on;
    float r   = dr * dr;
    float den = (r_c - r_o);
    float t   = r_c - r;
    float inner = (dr < r_cut)
        ? (t * t * (r_c + 2.0f * r - 3.0f * r_o)) / (den * den * den)
        : 0.0f;
    return (dr < r_on) ? 1.0f : inner;
}

__device__ __forceinline__ float edge_m(float dr, float rc) {
    if (!(dr > 0.0f)) return 0.0f;
    float count = 1.0f / (1.0f + expf(-KCN_F * (rc / dr - 1.0f)));
    return smooth_cutoff(dr, 20.0f, 25.0f) * count;
}

__device__ __forceinline__ void u2f2(unsigned u, float& a, float& b) {
    __half2 h = __builtin_bit_cast(__half2, u);
    float2 f = __half22float2(h);
    a = f.x; b = f.y;
}

__device__ __forceinline__ int zfromR(uint4 R) {
    float z, dum;
    u2f2(R.w, z, dum);
    return (int)z;
}

// per-edge energy: fp16 atom records + u8-quantized c6 row (2 x uint4).
// c6 row layout (32B): bytes 0..24 = u8 quant, 25..27 pad, 28..31 = f32 scale.
__device__ __forceinline__ float edge_e8(float dr, uint4 Ri, uint4 Rj,
                                         uint4 c0, uint4 c1) {
    float wi[5], wj[5], qi, qj;
    u2f2(Ri.x, wi[0], wi[1]); u2f2(Ri.y, wi[2], wi[3]); u2f2(Ri.z, wi[4], qi);
    u2f2(Rj.x, wj[0], wj[1]); u2f2(Rj.y, wj[2], wj[3]); u2f2(Rj.z, wj[4], qj);
    unsigned w[7] = { c0.x, c0.y, c0.z, c0.w, c1.x, c1.y, c1.z };
    float sc = __uint_as_float(c1.w);
    float c6q = 0.0f;
#pragma unroll
    for (int a = 0; a < 5; ++a) {
#pragma unroll
        for (int b = 0; b < 5; ++b) {
            const int k = a * 5 + b;
            float qv = (float)((w[k >> 2] >> ((k & 3) * 8)) & 0xFFu);
            c6q += wj[a] * wi[b] * qv;
        }
    }
    float c6 = c6q * sc;
    float qq = 3.0f * qi * qj;
    float rr = A1_F * sqrtf(qq) + A2_F;
    float dr2 = dr * dr;
    float dr6 = dr2 * dr2 * dr2;
    float dr8 = dr6 * dr2;
    float rr2 = rr * rr;
    float rr6 = rr2 * rr2 * rr2;
    float rr8 = rr6 * rr2;
    float damped = -c6 * (S6_F / (dr6 + rr6) + S8_F * qq / (dr8 + rr8));
    return smooth_cutoff(dr, 55.0f, 60.0f) * damped * 0.5f;
}

// ---------------- prep ----------------
// quantize ref_c6 rows: [95*95][25] f32 -> [95*95][32B] {25 u8, pad, f32 scale}
__global__ __launch_bounds__(256)
void k_prep_c6u8(const float* __restrict__ src, unsigned char* __restrict__ dst,
                 int nrows) {
    int r = blockIdx.x * blockDim.x + threadIdx.x;
    if (r >= nrows) return;
    const float* s = src + (size_t)r * 25;
    float mx = 0.0f;
#pragma unroll
    for (int k = 0; k < 25; ++k) mx = fmaxf(mx, fabsf(s[k]));
    float sc  = mx * (1.0f / 255.0f);
    float inv = (mx > 0.0f) ? 255.0f / mx : 0.0f;
    unsigned w[8];
#pragma unroll
    for (int v = 0; v < 7; ++v) {
        unsigned acc = 0;
#pragma unroll
        for (int b = 0; b < 4; ++b) {
            int k = v * 4 + b;
            unsigned q = 0;
            if (k < 25) {
                float t = s[k] * inv;
                t = fmaxf(t, 0.0f);
                q = (unsigned)(t + 0.5f);
                if (q > 255u) q = 255u;
            }
            acc |= q << (b * 8);
        }
        w[v] = acc;
    }
    w[7] = __float_as_uint(sc);
    uint4* d = reinterpret_cast<uint4*>(dst + (size_t)r * 32);
    d[0] = make_uint4(w[0], w[1], w[2], w[3]);
    d[1] = make_uint4(w[4], w[5], w[6], w[7]);
}

// rcovZ[a] = {f32 rcov[numbers[a]], u32 numbers[a]}
__global__ __launch_bounds__(256)
void k_prep_atom(const int* __restrict__ numbers, const float* __restrict__ rcov,
                 uint2* __restrict__ rcovZ, int n_atoms) {
    int a = blockIdx.x * blockDim.x + threadIdx.x;
    if (a >= n_atoms) return;
    int Z = numbers[a];
    rcovZ[a] = make_uint2(__float_as_uint(rcov[Z]), (unsigned)Z);
}

// ---------------- sort path ----------------
// Pass A: histogram only (streams idx_i). MUST share grid/block + edge
// mapping with k_scatter_full.
__global__ __launch_bounds__(BSW, 4)
void k_hist(const int* __restrict__ idx_i, unsigned* __restrict__ ghist,
            int n_edges, int nb) {
    __shared__ unsigned hist[256];
    if (threadIdx.x < 256) hist[threadIdx.x] = 0;
    __syncthreads();
    int nquad = n_edges >> 2;
    int tid = blockIdx.x * blockDim.x + threadIdx.x;
    int stride = gridDim.x * blockDim.x;
    for (int qd = tid; qd < nquad; qd += stride) {
        int4 i4 = *reinterpret_cast<const int4*>(idx_i + (qd << 2));
        atomicAdd(&hist[i4.x >> 9], 1u);
        atomicAdd(&hist[i4.y >> 9], 1u);
        atomicAdd(&hist[i4.z >> 9], 1u);
        atomicAdd(&hist[i4.w >> 9], 1u);
    }
    for (int e = (nquad << 2) + tid; e < n_edges; e += stride)
        atomicAdd(&hist[idx_i[e] >> 9], 1u);
    __syncthreads();
    if ((int)threadIdx.x < nb)
        ghist[(size_t)threadIdx.x * gridDim.x + blockIdx.x] = hist[threadIdx.x];
}

// Pass B1: per-bucket exclusive scan across NBLK block-counts; bucket totals.
__global__ __launch_bounds__(NBLK)
void k_scan_bucket(unsigned* __restrict__ ghist, unsigned* __restrict__ totals) {
    __shared__ unsigned s[NBLK];
    int b = blockIdx.x;
    int t = threadIdx.x;
    unsigned v = ghist[(size_t)b * NBLK + t];
    s[t] = v;
    __syncthreads();
    for (int off = 1; off < NBLK; off <<= 1) {
        unsigned x = (t >= off) ? s[t - off] : 0u;
        __syncthreads();
        s[t] += x;
        __syncthreads();
    }
    ghist[(size_t)b * NBLK + t] = s[t] - v;   // exclusive
    if (t == NBLK - 1) totals[b] = s[t];
}

// Pass B2: exclusive scan over bucket totals -> base[nb+1].
__global__ __launch_bounds__(256)
void k_scan_base(const unsigned* __restrict__ totals,
                 unsigned* __restrict__ base, int nb) {
    __shared__ unsigned s[256];
    int t = threadIdx.x;
    unsigned v = (t < nb) ? totals[t] : 0u;
    s[t] = v;
    __syncthreads();
    for (int off = 1; off < 256; off <<= 1) {
        unsigned x = (t >= off) ? s[t - off] : 0u;
        __syncthreads();
        s[t] += x;
        __syncthreads();
    }
    if (t < nb) base[t] = s[t] - v;
    if (t == 255) base[nb] = s[t];
}

// Pass C: full per-edge compute + direct scatter into sorted order.
__global__ __launch_bounds__(BSW, 4)
void k_scatter_full(const float* __restrict__ dr_vec,
                    const int* __restrict__ idx_i,
                    const int* __restrict__ idx_j,
                    const uint2* __restrict__ rcovZ,
                    const unsigned* __restrict__ ghist,
                    const unsigned* __restrict__ base,
                    uint2* __restrict__ pairs,
                    int n_edges, int nb) {
    __shared__ unsigned ofs[256];
    if ((int)threadIdx.x < nb)
        ofs[threadIdx.x] = base[threadIdx.x]
                         + ghist[(size_t)threadIdx.x * gridDim.x + blockIdx.x];
    __syncthreads();
    int nquad = n_edges >> 2;
    int tid = blockIdx.x * blockDim.x + threadIdx.x;
    int stride = gridDim.x * blockDim.x;
    for (int qd = tid; qd < nquad; qd += stride) {
        int e0 = qd << 2;
        float4 v0 = *reinterpret_cast<const float4*>(dr_vec + 3 * e0);
        float4 v1 = *reinterpret_cast<const float4*>(dr_vec + 3 * e0 + 4);
        float4 v2 = *reinterpret_cast<const float4*>(dr_vec + 3 * e0 + 8);
        float drq[4];
        drq[0] = sqrtf(v0.x*v0.x + v0.y*v0.y + v0.z*v0.z) / BOHR_F;
        drq[1] = sqrtf(v0.w*v0.w + v1.x*v1.x + v1.y*v1.y) / BOHR_F;
        drq[2] = sqrtf(v1.z*v1.z + v1.w*v1.w + v2.x*v2.x) / BOHR_F;
        drq[3] = sqrtf(v2.y*v2.y + v2.z*v2.z + v2.w*v2.w) / BOHR_F;
        int4 i4 = *reinterpret_cast<const int4*>(idx_i + e0);
        int4 j4 = *reinterpret_cast<const int4*>(idx_j + e0);
        int ia[4] = { i4.x, i4.y, i4.z, i4.w };
        int ja[4] = { j4.x, j4.y, j4.z, j4.w };
        uint2 RiZ[4], RjZ[4];
#pragma unroll
        for (int k = 0; k < 4; ++k) { RiZ[k] = rcovZ[ia[k]]; RjZ[k] = rcovZ[ja[k]]; }
#pragma unroll
        for (int k = 0; k < 4; ++k) {
            float rc = __uint_as_float(RiZ[k].x) + __uint_as_float(RjZ[k].x);
            float m = edge_m(drq[k], rc);
            unsigned q = (unsigned)(m * Q15_SCALE + 0.5f);
            if (q > 0x7FFFu) q = 0x7FFFu;
            unsigned dq = (unsigned)(drq[k] * DR_SCALE + 0.5f);
            if (dq > 0x7FFFu) dq = 0x7FFFu;
            unsigned w0 = ((unsigned)ia[k] << 15) | q;
            unsigned w1 = ((unsigned)ja[k] << 15) | dq;
            unsigned pos = atomicAdd(&ofs[ia[k] >> 9], 1u);
            pairs[pos] = make_uint2(w0, w1);
        }
    }
    // tail (same mapping as k_hist tail)
    for (int e = (nquad << 2) + tid; e < n_edges; e += stride) {
        float x = dr_vec[3*e], y = dr_vec[3*e+1], z = dr_vec[3*e+2];
        float dr = sqrtf(x*x + y*y + z*z) / BOHR_F;
        int i = idx_i[e], j = idx_j[e];
        uint2 RiZ = rcovZ[i], RjZ = rcovZ[j];
        float m = edge_m(dr, __uint_as_float(RiZ.x) + __uint_as_float(RjZ.x));
        unsigned q = (unsigned)(m * Q15_SCALE + 0.5f);
        if (q > 0x7FFFu) q = 0x7FFFu;
        unsigned dq = (unsigned)(dr * DR_SCALE + 0.5f);
        if (dq > 0x7FFFu) dq = 0x7FFFu;
        unsigned pos = atomicAdd(&ofs[i >> 9], 1u);
        pairs[pos] = make_uint2(((unsigned)i << 15) | q,
                                ((unsigned)j << 15) | dq);
    }
}

// Pass D: per-bucket LDS reduce -> cn; fused weights -> rec {w0..4, r4r2, Z, 0}
__global__ __launch_bounds__(512)
void k_reduce_weights(const uint2* __restrict__ pairs,
                      const unsigned* __restrict__ base,
                      const int* __restrict__ numbers,
                      const float* __restrict__ ref_cn_table,
                      const float* __restrict__ r4r2,
                      __half* __restrict__ rec,
                      int n_atoms) {
    __shared__ unsigned hist[512];
    hist[threadIdx.x] = 0;
    __syncthreads();
    int b = blockIdx.x;
    unsigned start = base[b];
    unsigned end   = base[b + 1];
    for (unsigned k = start + threadIdx.x; k < end; k += 512) {
        unsigned p = pairs[k].x;
        atomicAdd(&hist[(p >> 15) & 511], p & 0x7FFFu);
    }
    __syncthreads();
    int a = (b << 9) + threadIdx.x;
    if (a < n_atoms) {
        float c = (float)hist[threadIdx.x] * Q15_INV;
        int Z = numbers[a];
        float w[5];
        float s = 0.0f;
#pragma unroll
        for (int r = 0; r < 5; ++r) {
            float rcn = ref_cn_table[Z * 5 + r];
            float d = rcn - c;
            float wv = (rcn >= 0.0f) ? expf(-WF_F * d * d) : 0.0f;
            w[r] = wv;
            s += wv;
        }
        float den = s + EPS_F;
        __half* rr = rec + (size_t)a * 8;
#pragma unroll
        for (int r = 0; r < 5; ++r) rr[r] = __float2half(w[r] / den);
        rr[5] = __float2half(r4r2[Z]);
        rr[6] = __float2half((float)Z);
        rr[7] = __float2half(0.0f);
    }
}

// ---------------- energy (sorted order, 4-edge batch, u8 c6) ----------------
#define LOADC8(p, z) do { \
    const uint4* _cp = reinterpret_cast<const uint4*>(c6q + (size_t)(z) * 32); \
    p##0 = _cp[0]; p##1 = _cp[1]; } while (0)

__global__ __launch_bounds__(256, 1)
void k_energy_sorted(const uint2* __restrict__ pairs,
                     const __half* __restrict__ rec,            // [N,8] halfs
                     const unsigned char* __restrict__ c6q,     // [95*95][32B]
                     double* __restrict__ e_acc,
                     int n_edges) {
    double local = 0.0;
    const uint4* recv = reinterpret_cast<const uint4*>(rec);
    int nquad = n_edges >> 2;
    int tid = blockIdx.x * blockDim.x + threadIdx.x;
    int stride = gridDim.x * blockDim.x;
    for (int qd = tid; qd < nquad; qd += stride) {
        int e0 = qd << 2;
        uint4 pA = *reinterpret_cast<const uint4*>(pairs + e0);
        uint4 pB = *reinterpret_cast<const uint4*>(pairs + e0 + 2);
        unsigned i0 = pA.x >> 15, j0 = pA.y >> 15;
        unsigned i1 = pA.z >> 15, j1 = pA.w >> 15;
        unsigned i2 = pB.x >> 15, j2 = pB.y >> 15;
        unsigned i3 = pB.z >> 15, j3 = pB.w >> 15;
        float dr0 = (float)(pA.y & 0x7FFFu) * DR_INV;
        float dr1 = (float)(pA.w & 0x7FFFu) * DR_INV;
        float dr2 = (float)(pB.y & 0x7FFFu) * DR_INV;
        float dr3 = (float)(pB.w & 0x7FFFu) * DR_INV;
        uint4 Ri0 = recv[i0], Rj0 = recv[j0];
        uint4 Ri1 = recv[i1], Rj1 = recv[j1];
        uint4 Ri2 = recv[i2], Rj2 = recv[j2];
        uint4 Ri3 = recv[i3], Rj3 = recv[j3];
        int zp0 = zfromR(Rj0) * NELEM + zfromR(Ri0);
        int zp1 = zfromR(Rj1) * NELEM + zfromR(Ri1);
        int zp2 = zfromR(Rj2) * NELEM + zfromR(Ri2);
        int zp3 = zfromR(Rj3) * NELEM + zfromR(Ri3);
        uint4 a0, a1;   LOADC8(a, zp0);
        uint4 b0, b1;   LOADC8(b, zp1);
        uint4 c0, c1;   LOADC8(c, zp2);
        uint4 d0, d1;   LOADC8(d, zp3);
        local += (double)edge_e8(dr0, Ri0, Rj0, a0, a1);
        local += (double)edge_e8(dr1, Ri1, Rj1, b0, b1);
        local += (double)edge_e8(dr2, Ri2, Rj2, c0, c1);
        local += (double)edge_e8(dr3, Ri3, Rj3, d0, d1);
    }
    for (int e = (nquad << 2) + tid; e < n_edges; e += stride) {
        uint2 pr = pairs[e];
        unsigned i = pr.x >> 15;
        unsigned j = pr.y >> 15;
        float dr = (float)(pr.y & 0x7FFFu) * DR_INV;
        uint4 Ri = recv[i];
        uint4 Rj = recv[j];
        int zp = zfromR(Rj) * NELEM + zfromR(Ri);
        const uint4* cp = reinterpret_cast<const uint4*>(c6q + (size_t)zp * 32);
        local += (double)edge_e8(dr, Ri, Rj, cp[0], cp[1]);
    }

    __shared__ double sdata[4];
    for (int off = 32; off > 0; off >>= 1)
        local += __shfl_down(local, off, 64);
    int lane = threadIdx.x & 63;
    int wid  = threadIdx.x >> 6;
    if (lane == 0) sdata[wid] = local;
    __syncthreads();
    if (threadIdx.x == 0) {
        double s = sdata[0] + sdata[1] + sdata[2] + sdata[3];
        atomicAdd(e_acc, s);
    }
}

// ---------------- atomic fallback path (small ws only) ----------------
__global__ __launch_bounds__(256)
void k_edges_cn_atomic(const float* __restrict__ dr_vec,
                       const int* __restrict__ idx_i,
                       const int* __restrict__ idx_j,
                       const uint2* __restrict__ rcovZ,
                       unsigned* __restrict__ cn_u32,
                       int n_edges) {
    int e = blockIdx.x * blockDim.x + threadIdx.x;
    if (e >= n_edges) return;
    float x = dr_vec[3 * e + 0];
    float y = dr_vec[3 * e + 1];
    float z = dr_vec[3 * e + 2];
    float dr = sqrtf(x * x + y * y + z * z) / BOHR_F;
    int i = idx_i[e];
    int j = idx_j[e];
    uint2 RiZ = rcovZ[i], RjZ = rcovZ[j];
    float m = edge_m(dr, __uint_as_float(RiZ.x) + __uint_as_float(RjZ.x));
    unsigned q = (unsigned)(m * CN_SCALE + 0.5f);
    if (q) atomicAdd(&cn_u32[i], q);
}

__global__ __launch_bounds__(256)
void k_atom_weights_rec(const unsigned* __restrict__ cn_u32,
                        const int* __restrict__ numbers,
                        const float* __restrict__ ref_cn_table,
                        const float* __restrict__ r4r2,
                        __half* __restrict__ rec,
                        int n_atoms) {
    int a = blockIdx.x * blockDim.x + threadIdx.x;
    if (a >= n_atoms) return;
    float c = (float)cn_u32[a] * CN_INV;
    int Z = numbers[a];
    float w[5];
    float s = 0.0f;
#pragma unroll
    for (int r = 0; r < 5; ++r) {
        float rcn = ref_cn_table[Z * 5 + r];
        float d = rcn - c;
        float wv = (rcn >= 0.0f) ? expf(-WF_F * d * d) : 0.0f;
        w[r] = wv;
        s += wv;
    }
    float den = s + EPS_F;
    __half* rr = rec + (size_t)a * 8;
#pragma unroll
    for (int r = 0; r < 5; ++r) rr[r] = __float2half(w[r] / den);
    rr[5] = __float2half(r4r2[Z]);
    rr[6] = __float2half((float)Z);
    rr[7] = __float2half(0.0f);
}

__global__ __launch_bounds__(256)
void k_energy_unsorted(const float* __restrict__ dr_vec,
                       const int* __restrict__ idx_i,
                       const int* __restrict__ idx_j,
                       const __half* __restrict__ rec,
                       const unsigned char* __restrict__ c6q,
                       double* __restrict__ e_acc,
                       int n_edges) {
    double local = 0.0;
    const uint4* recv = reinterpret_cast<const uint4*>(rec);
    int tid = blockIdx.x * blockDim.x + threadIdx.x;
    int stride = gridDim.x * blockDim.x;
    for (int e = tid; e < n_edges; e += stride) {
        float x = dr_vec[3*e], y = dr_vec[3*e+1], z = dr_vec[3*e+2];
        float dr = sqrtf(x*x + y*y + z*z) / BOHR_F;
        int i = idx_i[e], j = idx_j[e];
        uint4 Ri = recv[i];
        uint4 Rj = recv[j];
        int zp = zfromR(Rj) * NELEM + zfromR(Ri);
        const uint4* cp = reinterpret_cast<const uint4*>(c6q + (size_t)zp * 32);
        local += (double)edge_e8(dr, Ri, Rj, cp[0], cp[1]);
    }
    __shared__ double sdata[4];
    for (int off = 32; off > 0; off >>= 1)
        local += __shfl_down(local, off, 64);
    int lane = threadIdx.x & 63;
    int wid  = threadIdx.x >> 6;
    if (lane == 0) sdata[wid] = local;
    __syncthreads();
    if (threadIdx.x == 0) {
        double s = sdata[0] + sdata[1] + sdata[2] + sdata[3];
        atomicAdd(e_acc, s);
    }
}

__global__ void k_finalize(const double* __restrict__ e_acc,
                           float* __restrict__ out) {
    out[0] = (float)(e_acc[0] * HA_D);
}

static inline size_t a16(size_t x) { return (x + 15) & ~(size_t)15; }

extern "C" void kernel_launch(void* const* d_in, const int* in_sizes, int n_in,
                              void* d_out, int out_size, void* d_ws, size_t ws_size,
                              hipStream_t stream) {
    const float* dr_vec      = (const float*)d_in[0];
    const float* ref_cn_tab  = (const float*)d_in[1];
    const float* ref_c6_tab  = (const float*)d_in[2];
    const float* r4r2        = (const float*)d_in[3];
    const float* rcov        = (const float*)d_in[4];
    const int*   numbers     = (const int*)d_in[5];
    const int*   idx         = (const int*)d_in[6];

    int n_atoms = in_sizes[5];
    int n_edges = in_sizes[6] / 2;
    const int* idx_i = idx;
    const int* idx_j = idx + n_edges;

    const int BS = 256;
    int nb = (n_atoms + 511) >> 9;
    int nrows = NELEM * NELEM;

    char* ws = (char*)d_ws;
    double* e_acc = (double*)ws;

    // common prefix: [e_acc 16][rec N*16B][c6q rows*32B][rcovZ N*8]
    size_t off_rec = 16;
    size_t off_c6q = a16(off_rec + (size_t)n_atoms * 8 * 2);
    size_t off_rcZ = a16(off_c6q + (size_t)nrows * 32);
    size_t off_var = a16(off_rcZ + (size_t)n_atoms * 8);

    // sort path: [pairs 8E][ghist][tot][base]
    size_t s_pairs  = off_var;
    size_t s_ghist  = a16(s_pairs + (size_t)n_edges * 8);
    size_t s_tot    = a16(s_ghist + (size_t)nb * NBLK * 4);
    size_t s_base   = a16(s_tot + (size_t)nb * 4);
    size_t need_s   = s_base + (size_t)(nb + 1) * 4;

    // atomic path: [cn N*4]
    size_t a_cn   = off_var;

    int grid_r  = (nrows + BS - 1) / BS;
    int grid_a  = (n_atoms + BS - 1) / BS;
    int nquad   = (n_edges + 3) >> 2;
    int grid_q  = (nquad + BS - 1) / BS;
    if (grid_q > 8192) grid_q = 8192;
    int grid_e1 = (n_edges + BS - 1) / BS;
    if (grid_e1 > 8192) grid_e1 = 8192;

    __half*        rec   = (__half*)(ws + off_rec);
    unsigned char* c6q   = (unsigned char*)(ws + off_c6q);
    uint2*         rcovZ = (uint2*)(ws + off_rcZ);

    k_prep_c6u8<<<grid_r, BS, 0, stream>>>(ref_c6_tab, c6q, nrows);
    k_prep_atom<<<grid_a, BS, 0, stream>>>(numbers, rcov, rcovZ, n_atoms);

    bool sortable = (n_atoms <= (1 << 17)) && (nb <= 256);

    if (sortable && ws_size >= need_s) {
        uint2*    pairs   = (uint2*)(ws + s_pairs);
        unsigned* ghist   = (unsigned*)(ws + s_ghist);
        unsigned* totals  = (unsigned*)(ws + s_tot);
        unsigned* base    = (unsigned*)(ws + s_base);

        hipMemsetAsync(d_ws, 0, 16, stream);   // e_acc only

        k_hist<<<NBLK, BSW, 0, stream>>>(idx_i, ghist, n_edges, nb);
        k_scan_bucket<<<nb, NBLK, 0, stream>>>(ghist, totals);
        k_scan_base<<<1, 256, 0, stream>>>(totals, base, nb);
        k_scatter_full<<<NBLK, BSW, 0, stream>>>(dr_vec, idx_i, idx_j, rcovZ,
            ghist, base, pairs, n_edges, nb);
        k_reduce_weights<<<nb, 512, 0, stream>>>(pairs, base, numbers,
            ref_cn_tab, r4r2, rec, n_atoms);
        k_energy_sorted<<<grid_q, BS, 0, stream>>>(pairs, rec, c6q, e_acc,
                                                   n_edges);
    } else {
        unsigned* cn_u32 = (unsigned*)(ws + a_cn);
        hipMemsetAsync(d_ws, 0, 16, stream);
        hipMemsetAsync(cn_u32, 0, (size_t)n_atoms * 4, stream);

        int grid_e = (n_edges + BS - 1) / BS;
        k_edges_cn_atomic<<<grid_e, BS, 0, stream>>>(dr_vec, idx_i, idx_j,
            rcovZ, cn_u32, n_edges);
        k_atom_weights_rec<<<grid_a, BS, 0, stream>>>(cn_u32, numbers,
            ref_cn_tab, r4r2, rec, n_atoms);
        k_energy_unsorted<<<grid_e1, BS, 0, stream>>>(dr_vec, idx_i, idx_j,
            rec, c6q, e_acc, n_edges);
    }

    k_finalize<<<1, 1, 0, stream>>>(e_acc, (float*)d_out);
}